// Round 4
// baseline (5973.655 us; speedup 1.0000x reference)
//
#include <hip/hip_runtime.h>
#include <math.h>

#define N_NODES 50000
#define N_EDGES 800000
#define IN_C    256
#define HID     96
#define OUT_C   64
#define NLAYER  3
#define XSP     100     // xs row stride in floats (pad breaks stride-96 bank collide)
#define NT      96      // nodes per block-group

// 16 FMAs: one x-row float4 against 4 W-row float4s into acc row AR[0..3]
#define FMA_ROW(xv, w0, w1, w2, w3, AR) \
    AR[0]=fmaf(xv.x,w0.x,AR[0]); AR[1]=fmaf(xv.x,w0.y,AR[1]); AR[2]=fmaf(xv.x,w0.z,AR[2]); AR[3]=fmaf(xv.x,w0.w,AR[3]); \
    AR[0]=fmaf(xv.y,w1.x,AR[0]); AR[1]=fmaf(xv.y,w1.y,AR[1]); AR[2]=fmaf(xv.y,w1.z,AR[2]); AR[3]=fmaf(xv.y,w1.w,AR[3]); \
    AR[0]=fmaf(xv.z,w2.x,AR[0]); AR[1]=fmaf(xv.z,w2.y,AR[1]); AR[2]=fmaf(xv.z,w2.z,AR[2]); AR[3]=fmaf(xv.z,w2.w,AR[3]); \
    AR[0]=fmaf(xv.w,w3.x,AR[0]); AR[1]=fmaf(xv.w,w3.y,AR[1]); AR[2]=fmaf(xv.w,w3.z,AR[2]); AR[3]=fmaf(xv.w,w3.w,AR[3]);

// ---------------- CSR build ----------------
// NOTE: harness passes integer inputs as int32.

__global__ void k_init(int* cnt, int* cur, int* counter,
                       int* col, float* wgt, int n) {
    int v = blockIdx.x * blockDim.x + threadIdx.x;
    if (v < n) { cnt[v] = 0; cur[v] = 0; }
    if (v == 0) *counter = 0;
    if (v < 16) { col[N_EDGES + v] = 0; wgt[N_EDGES + v] = 0.f; }  // pad for unroll-16 overread
}

__global__ void k_count(const int* __restrict__ ei, int* cnt, int e) {
    int i = blockIdx.x * blockDim.x + threadIdx.x;
    if (i < e) atomicAdd(&cnt[ei[e + i]], 1);   // row 1 = dst
}

__global__ void k_node(const int* __restrict__ cnt, float* __restrict__ dis,
                       int* __restrict__ start, int* counter, int n) {
    int v = blockIdx.x * blockDim.x + threadIdx.x;
    if (v < n) {
        int c = cnt[v];
        dis[v] = (float)(1.0 / sqrt((double)(c + 1)));  // deg incl self-loop >= 1
        start[v] = atomicAdd(counter, c);
    }
}

__global__ void k_fill(const int* __restrict__ ei, const float* __restrict__ dis,
                       const int* __restrict__ start, int* __restrict__ cur,
                       int* __restrict__ col, float* __restrict__ wgt, int e) {
    int i = blockIdx.x * blockDim.x + threadIdx.x;
    if (i < e) {
        int s = ei[i];
        int d = ei[e + i];
        int slot = start[d] + atomicAdd(&cur[d], 1);
        col[slot] = s;
        wgt[slot] = dis[s] * dis[d];
    }
}

// ---------------- generic dense: C[N x 96] = f(A[N x K]) @ W[K x 96] (+bias) ----
// K is a TEMPLATE param -> all loop bounds compile-time -> full unroll, compiler
// software-pipelines W loads + batches waitcnts (runtime trip counts were the
// R1/R3 84-us wall suspect). 96 nodes/block (grid 521 = 2.03 blocks/CU, perfect
// 2-resident packing); per-thread tile 6 nodes x 4 outputs; LDS = x tile only
// (38.4 KB); W streamed from global (L1/L2-resident).

template<int K, bool QUANT, bool BIAS>
__global__ __launch_bounds__(384, 3) void k_gemm(
    const float* __restrict__ A, int lda,
    const float* __restrict__ bn, float delta, float inv_delta,
    const float* __restrict__ W, const float* __restrict__ bias,
    float* __restrict__ C)
{
    __shared__ float xs[NT * XSP];      // 38.4 KB
    const int t  = threadIdx.x;
    const int og = t % 24;              // outputs 4og..4og+3
    const int rg = t / 24;              // nodes 6rg..6rg+5 (within group)
    constexpr int NCH = (K + 95) / 96;
    const int ngroups = (N_NODES + NT - 1) / NT;

    const float* Wt = W + 4 * og;       // column base for this thread's 4 outputs

    float4 bv = make_float4(0.f, 0.f, 0.f, 0.f);
    if (BIAS) bv = *(const float4*)&bias[4 * og];

    for (int g = blockIdx.x; g < ngroups; g += gridDim.x) {
        float acc[6][4];
        #pragma unroll
        for (int r = 0; r < 6; r++)
            #pragma unroll
            for (int o = 0; o < 4; o++) acc[r][o] = 0.f;

        #pragma unroll
        for (int ch = 0; ch < NCH; ch++) {
            const int kc0 = ch * 96;
            constexpr int KCW0 = 96;                     // full chunk
            const int kcw = (K - kc0 < 96) ? (K - kc0) : 96;
            const int nslot = kcw >> 4;                  // f4-slots per thread: 6 or 4
            __syncthreads();
            // stage NT rows x kcw cols; issue ALL loads before any LDS write
            {
                float4 va[6], vb[6];
                int nd[6], kq[6];
                #pragma unroll
                for (int j = 0; j < 6; j++) {
                    if (j < nslot) {
                        int i = t + 384 * j;
                        int kq4 = kcw >> 2;              // 24 or 16
                        nd[j] = i / kq4; kq[j] = i - nd[j] * kq4;
                        int gn = g * NT + nd[j];
                        int gc = gn < N_NODES ? gn : N_NODES - 1;
                        va[j] = *(const float4*)&A[(size_t)gc * lda + kc0 + 4 * kq[j]];
                        if (QUANT)
                            vb[j] = *(const float4*)&bn[(size_t)gc * HID + kc0 + 4 * kq[j]];
                    }
                }
                #pragma unroll
                for (int j = 0; j < 6; j++) {
                    if (j < nslot) {
                        float4 v = va[j];
                        if (QUANT) {
                            float bx = vb[j].x * delta, by = vb[j].y * delta;
                            float bz = vb[j].z * delta, bw = vb[j].w * delta;
                            v.x = floorf((v.x + bx) * inv_delta) * delta - bx;
                            v.y = floorf((v.y + by) * inv_delta) * delta - by;
                            v.z = floorf((v.z + bz) * inv_delta) * delta - bz;
                            v.w = floorf((v.w + bw) * inv_delta) * delta - bw;
                        }
                        if (g * NT + nd[j] >= N_NODES) v = make_float4(0.f, 0.f, 0.f, 0.f);
                        *(float4*)&xs[nd[j] * XSP + 4 * kq[j]] = v;
                    }
                }
            }
            __syncthreads();
            // compute: fully unrolled (kcw is compile-time after ch-unroll).
            // per 4-k: 4 global W f4 (L1-hit) + 6 LDS f4 + 96 FMA.
            const float* Wc = Wt + (size_t)kc0 * HID;
            #pragma unroll
            for (int k = 0; k < KCW0; k += 4) {
                if (k < kcw) {
                    float4 w0 = *(const float4*)&Wc[(k + 0) * HID];
                    float4 w1 = *(const float4*)&Wc[(k + 1) * HID];
                    float4 w2 = *(const float4*)&Wc[(k + 2) * HID];
                    float4 w3 = *(const float4*)&Wc[(k + 3) * HID];
                    #pragma unroll
                    for (int r = 0; r < 6; r++) {
                        float4 xv = *(const float4*)&xs[(6 * rg + r) * XSP + k];
                        FMA_ROW(xv, w0, w1, w2, w3, acc[r]);
                    }
                }
            }
        }
        // epilogue
        #pragma unroll
        for (int r = 0; r < 6; r++) {
            int gn = g * NT + 6 * rg + r;
            if (gn < N_NODES) {
                float4 c;
                c.x = acc[r][0] + bv.x;
                c.y = acc[r][1] + bv.y;
                c.z = acc[r][2] + bv.z;
                c.w = acc[r][3] + bv.w;
                *(float4*)&C[(size_t)gn * HID + 4 * og] = c;
            }
        }
    }
}

// ---------------- per-layer: h = relu(segment_sum + conv_b + eps) ----------------
// unroll-16: avg degree 16 -> typically ONE latency round of gathers per node
// (unchanged this round: control)

__global__ __launch_bounds__(384) void k_agg(const float* __restrict__ m,
                                             const int* __restrict__ col,
                                             const float* __restrict__ wgt,
                                             const int* __restrict__ start,
                                             const int* __restrict__ cnt,
                                             const float* __restrict__ dis,
                                             const float* __restrict__ cb,
                                             const float* __restrict__ eps,
                                             float* __restrict__ hout) {
    const int tx = threadIdx.x;
    const int d = blockIdx.x * 4 + threadIdx.y;   // 12500*4 == N_NODES exactly
    const int s0 = start[d], c = cnt[d];
    const float* mt = m + tx;
    float a[8];
    #pragma unroll
    for (int j = 0; j < 8; j++) a[j] = 0.f;
    for (int e = 0; e < c; e += 16) {
        int   idx[16];
        float wv[16];
        #pragma unroll
        for (int j = 0; j < 16; j++) {
            idx[j] = col[s0 + e + j];                       // pad-16 makes overread safe
            wv[j]  = (e + j < c) ? wgt[s0 + e + j] : 0.f;
        }
        #pragma unroll
        for (int j = 0; j < 16; j++)
            a[j & 7] = fmaf(mt[idx[j] * HID], wv[j], a[j & 7]);
    }
    float dv = dis[d];
    float s = ((a[0] + a[1]) + (a[2] + a[3])) + ((a[4] + a[5]) + (a[6] + a[7]));
    s = fmaf(mt[d * HID], dv * dv, s);            // self-loop
    s += cb[tx] + eps[(size_t)d * HID + tx];
    hout[(size_t)d * HID + tx] = fmaxf(s, 0.f);
}

// ---------------- out = concat(h0, h) @ out_w + out_b -----------------
// (unchanged this round: control)

__global__ __launch_bounds__(384) void k_out2(const float* __restrict__ h0,
                                              const float* __restrict__ h,
                                              const float* __restrict__ W,
                                              const float* __restrict__ bias,
                                              float* __restrict__ out) {
    __shared__ float xs[96 * XSP];      // 38.4 KB
    const int t  = threadIdx.x;
    const int og = t % 16;              // outputs 4og..4og+3 (of 64)
    const int rg = t / 16;              // nodes 4rg..4rg+3 (of 96)
    const int ngroups = (N_NODES + 95) / 96;   // 521

    const float* Wt = W + 4 * og;
    float4 bv = *(const float4*)&bias[4 * og];

    for (int g = blockIdx.x; g < ngroups; g += gridDim.x) {
        float acc[4][4];
        #pragma unroll
        for (int r = 0; r < 4; r++)
            #pragma unroll
            for (int o = 0; o < 4; o++) acc[r][o] = 0.f;

        #pragma unroll
        for (int ch = 0; ch < 2; ch++) {
            const float* src = ch ? h : h0;
            __syncthreads();
            // 96 rows x 24 f4 = 2304 slots = 6/thread, all loads issued first
            float4 va[6];
            int nd[6], kq[6];
            #pragma unroll
            for (int j = 0; j < 6; j++) {
                int i = t + 384 * j;
                nd[j] = i / 24; kq[j] = i - nd[j] * 24;
                int gn = g * 96 + nd[j];
                int gc = gn < N_NODES ? gn : N_NODES - 1;   // clamp; OOB rows never stored
                va[j] = *(const float4*)&src[(size_t)gc * HID + 4 * kq[j]];
            }
            #pragma unroll
            for (int j = 0; j < 6; j++)
                *(float4*)&xs[nd[j] * XSP + 4 * kq[j]] = va[j];
            __syncthreads();

            const float* Wc = Wt + (size_t)(ch * HID) * OUT_C;
            #pragma unroll
            for (int k = 0; k < HID; k += 4) {
                float4 w0 = *(const float4*)&Wc[(k + 0) * OUT_C];
                float4 w1 = *(const float4*)&Wc[(k + 1) * OUT_C];
                float4 w2 = *(const float4*)&Wc[(k + 2) * OUT_C];
                float4 w3 = *(const float4*)&Wc[(k + 3) * OUT_C];
                #pragma unroll
                for (int r = 0; r < 4; r++) {
                    float4 xv = *(const float4*)&xs[(4 * rg + r) * XSP + k];
                    FMA_ROW(xv, w0, w1, w2, w3, acc[r]);
                }
            }
        }
        // epilogue
        #pragma unroll
        for (int r = 0; r < 4; r++) {
            int gn = g * 96 + 4 * rg + r;
            if (gn < N_NODES) {
                float4 c;
                c.x = acc[r][0] + bv.x;
                c.y = acc[r][1] + bv.y;
                c.z = acc[r][2] + bv.z;
                c.w = acc[r][3] + bv.w;
                *(float4*)&out[(size_t)gn * OUT_C + 4 * og] = c;
            }
        }
    }
}

// ---------------- launch ----------------

extern "C" void kernel_launch(void* const* d_in, const int* in_sizes, int n_in,
                              void* d_out, int out_size, void* d_ws, size_t ws_size,
                              hipStream_t stream) {
    (void)in_sizes; (void)n_in; (void)out_size; (void)ws_size;
    const float* x       = (const float*)d_in[0];
    const int*   ei      = (const int*)d_in[1];     // int32 per harness convention
    const float* proj_w  = (const float*)d_in[2];
    const float* proj_b  = (const float*)d_in[3];
    const float* conv_w  = (const float*)d_in[4];
    const float* conv_b  = (const float*)d_in[5];
    const float* out_w   = (const float*)d_in[6];
    const float* out_b   = (const float*)d_in[7];
    const float* b_noise = (const float*)d_in[8];
    const float* eps_n   = (const float*)d_in[9];
    float*       out     = (float*)d_out;

    char* w = (char*)d_ws;
    size_t off = 0;
    auto alloc = [&](size_t bytes) -> char* {
        char* p = w + off;
        off = (off + bytes + 255) & ~(size_t)255;
        return p;
    };
    float* h0b   = (float*)alloc((size_t)N_NODES * HID * 4);
    float* hA    = (float*)alloc((size_t)N_NODES * HID * 4);
    float* mb    = (float*)alloc((size_t)N_NODES * HID * 4);
    float* dis   = (float*)alloc((size_t)N_NODES * 4);
    float* wgt   = (float*)alloc((size_t)(N_EDGES + 16) * 4);
    int*   col   = (int*)  alloc((size_t)(N_EDGES + 16) * 4);
    int*   cnt   = (int*)  alloc((size_t)N_NODES * 4);
    int*   cur   = (int*)  alloc((size_t)N_NODES * 4);
    int*   start = (int*)  alloc((size_t)N_NODES * 4);
    int*   ctr   = (int*)  alloc(256);

    // CSR build
    k_init <<<(N_NODES + 255) / 256, 256, 0, stream>>>(cnt, cur, ctr, col, wgt, N_NODES);
    k_count<<<(N_EDGES + 255) / 256, 256, 0, stream>>>(ei, cnt, N_EDGES);
    k_node <<<(N_NODES + 255) / 256, 256, 0, stream>>>(cnt, dis, start, ctr, N_NODES);
    k_fill <<<(N_EDGES + 255) / 256, 256, 0, stream>>>(ei, dis, start, cur, col, wgt, N_EDGES);

    const int ngroups = (N_NODES + NT - 1) / NT;    // 521

    // h0 = x @ proj_w + proj_b (K chunked 96+96+64, compile-time)
    k_gemm<IN_C, false, true><<<ngroups, 384, 0, stream>>>(
        x, IN_C, nullptr, 1.f, 1.f, proj_w, proj_b, h0b);

    const float deltas[NLAYER] = {1.0f, 0.5f, 0.25f};
    const float* hprev = h0b;
    for (int k = 0; k < NLAYER; k++) {
        float dlt = deltas[k];
        // m = quantize(h) @ conv_w[k]
        k_gemm<HID, true, false><<<ngroups, 384, 0, stream>>>(
            hprev, HID,
            b_noise + (size_t)k * N_NODES * HID, dlt, 1.0f / dlt,
            conv_w + (size_t)k * HID * HID, nullptr, mb);
        // h = relu(segment_sum(m) + conv_b + eps)   (reads only mb -> in-place hA ok)
        k_agg<<<N_NODES / 4, dim3(96, 4), 0, stream>>>(
            mb, col, wgt, start, cnt, dis,
            conv_b + (size_t)k * HID,
            eps_n + (size_t)k * N_NODES * HID, hA);
        hprev = hA;
    }

    k_out2<<<ngroups, 384, 0, stream>>>(h0b, hprev, out_w, out_b, out);
}

// Round 6
// 748.559 us; speedup vs baseline: 7.9802x; 7.9802x over previous
//
#include <hip/hip_runtime.h>
#include <math.h>

#define N_NODES 50000
#define N_EDGES 800000
#define IN_C    256
#define HID     96
#define OUT_C   64
#define NLAYER  3
#define KC      96      // K-chunk (x tile columns staged per pass)
#define XSP     100     // xs row stride in floats (pad breaks stride-96 bank collide)

// 16 FMAs: one x-row float4 against 4 W-row float4s into acc row AR[0..3]
#define FMA_ROW(xv, w0, w1, w2, w3, AR) \
    AR[0]=fmaf(xv.x,w0.x,AR[0]); AR[1]=fmaf(xv.x,w0.y,AR[1]); AR[2]=fmaf(xv.x,w0.z,AR[2]); AR[3]=fmaf(xv.x,w0.w,AR[3]); \
    AR[0]=fmaf(xv.y,w1.x,AR[0]); AR[1]=fmaf(xv.y,w1.y,AR[1]); AR[2]=fmaf(xv.y,w1.z,AR[2]); AR[3]=fmaf(xv.y,w1.w,AR[3]); \
    AR[0]=fmaf(xv.z,w2.x,AR[0]); AR[1]=fmaf(xv.z,w2.y,AR[1]); AR[2]=fmaf(xv.z,w2.z,AR[2]); AR[3]=fmaf(xv.z,w2.w,AR[3]); \
    AR[0]=fmaf(xv.w,w3.x,AR[0]); AR[1]=fmaf(xv.w,w3.y,AR[1]); AR[2]=fmaf(xv.w,w3.z,AR[2]); AR[3]=fmaf(xv.w,w3.w,AR[3]);

// ---------------- CSR build ----------------
// NOTE: harness passes integer inputs as int32.

__global__ void k_init(int* cnt, int* cur, int* counter,
                       int* col, float* wgt, int n) {
    int v = blockIdx.x * blockDim.x + threadIdx.x;
    if (v < n) { cnt[v] = 0; cur[v] = 0; }
    if (v == 0) *counter = 0;
    if (v < 16) { col[N_EDGES + v] = 0; wgt[N_EDGES + v] = 0.f; }  // pad for unroll-16 overread
}

__global__ void k_count(const int* __restrict__ ei, int* cnt, int e) {
    int i = blockIdx.x * blockDim.x + threadIdx.x;
    if (i < e) atomicAdd(&cnt[ei[e + i]], 1);   // row 1 = dst
}

__global__ void k_node(const int* __restrict__ cnt, float* __restrict__ dis,
                       int* __restrict__ start, int* counter, int n) {
    int v = blockIdx.x * blockDim.x + threadIdx.x;
    if (v < n) {
        int c = cnt[v];
        dis[v] = (float)(1.0 / sqrt((double)(c + 1)));  // deg incl self-loop >= 1
        start[v] = atomicAdd(counter, c);
    }
}

__global__ void k_fill(const int* __restrict__ ei, const float* __restrict__ dis,
                       const int* __restrict__ start, int* __restrict__ cur,
                       int* __restrict__ col, float* __restrict__ wgt, int e) {
    int i = blockIdx.x * blockDim.x + threadIdx.x;
    if (i < e) {
        int s = ei[i];
        int d = ei[e + i];
        int slot = start[d] + atomicAdd(&cur[d], 1);
        col[slot] = s;
        wgt[slot] = dis[s] * dis[d];
    }
}

// ---------------- proj: C[N x 96] = A[N x K] @ W[K x 96] + bias ----------------
// R3-proven structure (84 us): block 384 = 24og x 16rg, 64 nodes/block, 4x4 tile,
// xs-only LDS (25.6 KB), W streamed from global, wa/wb double-buffered k-loop.
// QOUT epilogue also writes hq = quantize(C, bnq, dq) for the fused layers.

template<bool QUANT, bool BIAS, bool QOUT>
__global__ __launch_bounds__(384) void k_gemm(
    const float* __restrict__ A, int lda, int K,
    const float* __restrict__ bn, float delta, float inv_delta,
    const float* __restrict__ W, const float* __restrict__ bias,
    float* __restrict__ C,
    const float* __restrict__ bnq, float dq, float inv_dq,
    float* __restrict__ Cq)
{
    __shared__ float xs[64 * XSP];      // 25.6 KB (only LDS use)
    const int t  = threadIdx.x;
    const int og = t % 24;              // outputs 4og..4og+3
    const int rg = t / 24;              // nodes 4rg..4rg+3 (within group)
    const int nch = (K + KC - 1) / KC;
    const int ngroups = (N_NODES + 63) / 64;

    const float* Wt = W + 4 * og;       // column base for this thread's 4 outputs

    float4 bv = make_float4(0.f, 0.f, 0.f, 0.f);
    if (BIAS) bv = *(const float4*)&bias[4 * og];

    for (int g = blockIdx.x; g < ngroups; g += gridDim.x) {
        float acc[4][4];
        #pragma unroll
        for (int r = 0; r < 4; r++)
            #pragma unroll
            for (int o = 0; o < 4; o++) acc[r][o] = 0.f;

        for (int ch = 0; ch < nch; ch++) {
            const int kc0 = ch * KC;
            const int kcw = (K - kc0 < KC) ? (K - kc0) : KC;
            const int kq4 = kcw >> 2;     // 24 (full chunk) or 16 (proj tail)
            __syncthreads();
            if (kq4 == 24) {
                // fixed mapping: 64 rows x 24 f4 = 1536 slots = 4/thread.
                float4 va[4], vb[4];
                int nd[4], kq[4];
                #pragma unroll
                for (int j = 0; j < 4; j++) {
                    int i = t + 384 * j;
                    nd[j] = i / 24; kq[j] = i - nd[j] * 24;
                    int gn = g * 64 + nd[j];
                    int gc = gn < N_NODES ? gn : N_NODES - 1;
                    va[j] = *(const float4*)&A[(size_t)gc * lda + kc0 + 4 * kq[j]];
                    if (QUANT)
                        vb[j] = *(const float4*)&bn[(size_t)gc * HID + kc0 + 4 * kq[j]];
                }
                #pragma unroll
                for (int j = 0; j < 4; j++) {
                    float4 v = va[j];
                    if (QUANT) {
                        float bx = vb[j].x * delta, by = vb[j].y * delta;
                        float bz = vb[j].z * delta, bw = vb[j].w * delta;
                        v.x = floorf((v.x + bx) * inv_delta) * delta - bx;
                        v.y = floorf((v.y + by) * inv_delta) * delta - by;
                        v.z = floorf((v.z + bz) * inv_delta) * delta - bz;
                        v.w = floorf((v.w + bw) * inv_delta) * delta - bw;
                    }
                    if (g * 64 + nd[j] >= N_NODES) v = make_float4(0.f, 0.f, 0.f, 0.f);
                    *(float4*)&xs[nd[j] * XSP + 4 * kq[j]] = v;
                }
            } else {
                // generic fallback (proj tail chunk, kq4==16)
                const int tot = 64 * kq4;
                for (int i = t; i < tot; i += 384) {
                    int node = i >> 4, kq = i & 15;
                    int gn = g * 64 + node;
                    float4 v = make_float4(0.f, 0.f, 0.f, 0.f);
                    if (gn < N_NODES) {
                        v = *(const float4*)&A[(size_t)gn * lda + kc0 + 4 * kq];
                        if (QUANT) {
                            float4 b = *(const float4*)&bn[(size_t)gn * HID + kc0 + 4 * kq];
                            float bx = b.x * delta, by = b.y * delta;
                            float bz = b.z * delta, bw = b.w * delta;
                            v.x = floorf((v.x + bx) * inv_delta) * delta - bx;
                            v.y = floorf((v.y + by) * inv_delta) * delta - by;
                            v.z = floorf((v.z + bz) * inv_delta) * delta - bz;
                            v.w = floorf((v.w + bw) * inv_delta) * delta - bw;
                        }
                    }
                    *(float4*)&xs[node * XSP + 4 * kq] = v;
                }
            }
            __syncthreads();
            // k-loop: kcw is 96 or 64 (both %8==0). Double-buffered W regs.
            const float* Wc = Wt + (size_t)kc0 * HID;
            float4 wa0 = *(const float4*)&Wc[0 * HID];
            float4 wa1 = *(const float4*)&Wc[1 * HID];
            float4 wa2 = *(const float4*)&Wc[2 * HID];
            float4 wa3 = *(const float4*)&Wc[3 * HID];
            for (int k = 0; k < kcw; k += 8) {
                float4 wb0 = *(const float4*)&Wc[(k + 4) * HID];
                float4 wb1 = *(const float4*)&Wc[(k + 5) * HID];
                float4 wb2 = *(const float4*)&Wc[(k + 6) * HID];
                float4 wb3 = *(const float4*)&Wc[(k + 7) * HID];
                #pragma unroll
                for (int r = 0; r < 4; r++) {
                    float4 xv = *(const float4*)&xs[(4 * rg + r) * XSP + k];
                    FMA_ROW(xv, wa0, wa1, wa2, wa3, acc[r]);
                }
                if (k + 8 < kcw) {
                    wa0 = *(const float4*)&Wc[(k + 8)  * HID];
                    wa1 = *(const float4*)&Wc[(k + 9)  * HID];
                    wa2 = *(const float4*)&Wc[(k + 10) * HID];
                    wa3 = *(const float4*)&Wc[(k + 11) * HID];
                }
                #pragma unroll
                for (int r = 0; r < 4; r++) {
                    float4 xv = *(const float4*)&xs[(4 * rg + r) * XSP + k + 4];
                    FMA_ROW(xv, wb0, wb1, wb2, wb3, acc[r]);
                }
            }
        }
        // epilogue
        #pragma unroll
        for (int r = 0; r < 4; r++) {
            int gn = g * 64 + 4 * rg + r;
            if (gn < N_NODES) {
                float4 c;
                c.x = acc[r][0] + bv.x;
                c.y = acc[r][1] + bv.y;
                c.z = acc[r][2] + bv.z;
                c.w = acc[r][3] + bv.w;
                *(float4*)&C[(size_t)gn * HID + 4 * og] = c;
                if (QOUT) {
                    float4 b = *(const float4*)&bnq[(size_t)gn * HID + 4 * og];
                    float bx = b.x * dq, by = b.y * dq;
                    float bz = b.z * dq, bw = b.w * dq;
                    float4 q;
                    q.x = floorf((c.x + bx) * inv_dq) * dq - bx;
                    q.y = floorf((c.y + by) * inv_dq) * dq - by;
                    q.z = floorf((c.z + bz) * inv_dq) * dq - bz;
                    q.w = floorf((c.w + bw) * inv_dq) * dq - bw;
                    *(float4*)&Cq[(size_t)gn * HID + 4 * og] = q;
                }
            }
        }
    }
}

// ---------------- fused layer: h_out = f(relu(segsum(hq)@W + cb + eps)) --------
// Uses segsum(hq@W) == segsum(hq)@W (linearity). Phase A: gather-aggregate the
// pre-quantized hq rows for this block's 64 dst nodes into LDS (k_agg pattern,
// unroll-16). Phase B: R3 GEMM pattern (sg tile vs W streamed from global).
// Epilogue: +cb +eps, relu, then (unless last layer) quantize with NEXT layer's
// noise so the next k_layer gathers a ready hq. Eliminates the m intermediate
// (one full N x 96 write+read per layer) and one dispatch per layer.

__global__ __launch_bounds__(384) void k_layer(
    const float* __restrict__ hq,
    const int* __restrict__ col, const float* __restrict__ wgt,
    const int* __restrict__ start, const int* __restrict__ cnt,
    const float* __restrict__ dis,
    const float* __restrict__ W,
    const float* __restrict__ cb,
    const float* __restrict__ eps,
    const float* __restrict__ bnq, float dq, float inv_dq,
    float* __restrict__ hout, int quant_out)
{
    __shared__ float sg[64 * XSP];      // 25.6 KB aggregate tile
    const int t = threadIdx.x;
    const int g = blockIdx.x;           // grid = 782, one 64-dst group per block

    // ---- phase A: aggregate 64 dst rows (threads: 96 feature-lanes x 4) ----
    {
        const int tx = t % 96;
        const int ty = t / 96;
        const float* ht = hq + tx;
        for (int i = 0; i < 16; i++) {
            int ld = ty * 16 + i;       // local dst 0..63
            int d  = g * 64 + ld;
            float s = 0.f;
            if (d < N_NODES) {
                int s0 = start[d], c = cnt[d];
                float a[8];
                #pragma unroll
                for (int j = 0; j < 8; j++) a[j] = 0.f;
                for (int e = 0; e < c; e += 16) {
                    int   idx[16];
                    float wv[16];
                    #pragma unroll
                    for (int j = 0; j < 16; j++) {
                        idx[j] = col[s0 + e + j];           // pad-16 makes overread safe
                        wv[j]  = (e + j < c) ? wgt[s0 + e + j] : 0.f;
                    }
                    #pragma unroll
                    for (int j = 0; j < 16; j++)
                        a[j & 7] = fmaf(ht[idx[j] * HID], wv[j], a[j & 7]);
                }
                float dv = dis[d];
                s = ((a[0] + a[1]) + (a[2] + a[3])) + ((a[4] + a[5]) + (a[6] + a[7]));
                s = fmaf(ht[d * HID], dv * dv, s);          // self-loop
            }
            sg[ld * XSP + tx] = s;
        }
    }
    __syncthreads();

    // ---- phase B: 64x96 tile @ W[96x96] (R3 dbuf k-loop) ----
    const int og = t % 24;
    const int rg = t / 24;
    const float* Wt = W + 4 * og;
    float acc[4][4];
    #pragma unroll
    for (int r = 0; r < 4; r++)
        #pragma unroll
        for (int o = 0; o < 4; o++) acc[r][o] = 0.f;

    float4 wa0 = *(const float4*)&Wt[0 * HID];
    float4 wa1 = *(const float4*)&Wt[1 * HID];
    float4 wa2 = *(const float4*)&Wt[2 * HID];
    float4 wa3 = *(const float4*)&Wt[3 * HID];
    for (int k = 0; k < HID; k += 8) {
        float4 wb0 = *(const float4*)&Wt[(k + 4) * HID];
        float4 wb1 = *(const float4*)&Wt[(k + 5) * HID];
        float4 wb2 = *(const float4*)&Wt[(k + 6) * HID];
        float4 wb3 = *(const float4*)&Wt[(k + 7) * HID];
        #pragma unroll
        for (int r = 0; r < 4; r++) {
            float4 xv = *(const float4*)&sg[(4 * rg + r) * XSP + k];
            FMA_ROW(xv, wa0, wa1, wa2, wa3, acc[r]);
        }
        if (k + 8 < HID) {
            wa0 = *(const float4*)&Wt[(k + 8)  * HID];
            wa1 = *(const float4*)&Wt[(k + 9)  * HID];
            wa2 = *(const float4*)&Wt[(k + 10) * HID];
            wa3 = *(const float4*)&Wt[(k + 11) * HID];
        }
        #pragma unroll
        for (int r = 0; r < 4; r++) {
            float4 xv = *(const float4*)&sg[(4 * rg + r) * XSP + k + 4];
            FMA_ROW(xv, wb0, wb1, wb2, wb3, acc[r]);
        }
    }

    // ---- epilogue: +cb +eps, relu, optional next-layer quantize ----
    float4 bv = *(const float4*)&cb[4 * og];
    #pragma unroll
    for (int r = 0; r < 4; r++) {
        int gn = g * 64 + 4 * rg + r;
        if (gn < N_NODES) {
            float4 ev = *(const float4*)&eps[(size_t)gn * HID + 4 * og];
            float4 h;
            h.x = fmaxf(acc[r][0] + bv.x + ev.x, 0.f);
            h.y = fmaxf(acc[r][1] + bv.y + ev.y, 0.f);
            h.z = fmaxf(acc[r][2] + bv.z + ev.z, 0.f);
            h.w = fmaxf(acc[r][3] + bv.w + ev.w, 0.f);
            if (quant_out) {
                float4 b = *(const float4*)&bnq[(size_t)gn * HID + 4 * og];
                float bx = b.x * dq, by = b.y * dq;
                float bz = b.z * dq, bw = b.w * dq;
                h.x = floorf((h.x + bx) * inv_dq) * dq - bx;
                h.y = floorf((h.y + by) * inv_dq) * dq - by;
                h.z = floorf((h.z + bz) * inv_dq) * dq - bz;
                h.w = floorf((h.w + bw) * inv_dq) * dq - bw;
            }
            *(float4*)&hout[(size_t)gn * HID + 4 * og] = h;
        }
    }
}

// ---------------- out = concat(h0, h) @ out_w + out_b -----------------
// k_gemm-style: block 384 = 16 og x 24 rg; 96 nodes/group; 2 chunks (h0, h);
// xs 38.4 KB LDS only; W (48 KB) streamed from global.

__global__ __launch_bounds__(384) void k_out2(const float* __restrict__ h0,
                                              const float* __restrict__ h,
                                              const float* __restrict__ W,
                                              const float* __restrict__ bias,
                                              float* __restrict__ out) {
    __shared__ float xs[96 * XSP];      // 38.4 KB
    const int t  = threadIdx.x;
    const int og = t % 16;              // outputs 4og..4og+3 (of 64)
    const int rg = t / 16;              // nodes 4rg..4rg+3 (of 96)
    const int ngroups = (N_NODES + 95) / 96;   // 521

    const float* Wt = W + 4 * og;
    float4 bv = *(const float4*)&bias[4 * og];

    for (int g = blockIdx.x; g < ngroups; g += gridDim.x) {
        float acc[4][4];
        #pragma unroll
        for (int r = 0; r < 4; r++)
            #pragma unroll
            for (int o = 0; o < 4; o++) acc[r][o] = 0.f;

        #pragma unroll
        for (int ch = 0; ch < 2; ch++) {
            const float* src = ch ? h : h0;
            __syncthreads();
            // 96 rows x 24 f4 = 2304 slots = 6/thread, all loads issued first
            float4 va[6];
            int nd[6], kq[6];
            #pragma unroll
            for (int j = 0; j < 6; j++) {
                int i = t + 384 * j;
                nd[j] = i / 24; kq[j] = i - nd[j] * 24;
                int gn = g * 96 + nd[j];
                int gc = gn < N_NODES ? gn : N_NODES - 1;   // clamp; OOB rows never stored
                va[j] = *(const float4*)&src[(size_t)gc * HID + 4 * kq[j]];
            }
            #pragma unroll
            for (int j = 0; j < 6; j++)
                *(float4*)&xs[nd[j] * XSP + 4 * kq[j]] = va[j];
            __syncthreads();

            const float* Wc = Wt + (size_t)(ch * HID) * OUT_C;
            float4 wa0 = *(const float4*)&Wc[0 * OUT_C];
            float4 wa1 = *(const float4*)&Wc[1 * OUT_C];
            float4 wa2 = *(const float4*)&Wc[2 * OUT_C];
            float4 wa3 = *(const float4*)&Wc[3 * OUT_C];
            for (int k = 0; k < HID; k += 8) {
                float4 wb0 = *(const float4*)&Wc[(k + 4) * OUT_C];
                float4 wb1 = *(const float4*)&Wc[(k + 5) * OUT_C];
                float4 wb2 = *(const float4*)&Wc[(k + 6) * OUT_C];
                float4 wb3 = *(const float4*)&Wc[(k + 7) * OUT_C];
                #pragma unroll
                for (int r = 0; r < 4; r++) {
                    float4 xv = *(const float4*)&xs[(4 * rg + r) * XSP + k];
                    FMA_ROW(xv, wa0, wa1, wa2, wa3, acc[r]);
                }
                if (k + 8 < HID) {
                    wa0 = *(const float4*)&Wc[(k + 8)  * OUT_C];
                    wa1 = *(const float4*)&Wc[(k + 9)  * OUT_C];
                    wa2 = *(const float4*)&Wc[(k + 10) * OUT_C];
                    wa3 = *(const float4*)&Wc[(k + 11) * OUT_C];
                }
                #pragma unroll
                for (int r = 0; r < 4; r++) {
                    float4 xv = *(const float4*)&xs[(4 * rg + r) * XSP + k + 4];
                    FMA_ROW(xv, wb0, wb1, wb2, wb3, acc[r]);
                }
            }
        }
        // epilogue
        #pragma unroll
        for (int r = 0; r < 4; r++) {
            int gn = g * 96 + 4 * rg + r;
            if (gn < N_NODES) {
                float4 c;
                c.x = acc[r][0] + bv.x;
                c.y = acc[r][1] + bv.y;
                c.z = acc[r][2] + bv.z;
                c.w = acc[r][3] + bv.w;
                *(float4*)&out[(size_t)gn * OUT_C + 4 * og] = c;
            }
        }
    }
}

// ---------------- launch ----------------

extern "C" void kernel_launch(void* const* d_in, const int* in_sizes, int n_in,
                              void* d_out, int out_size, void* d_ws, size_t ws_size,
                              hipStream_t stream) {
    (void)in_sizes; (void)n_in; (void)out_size; (void)ws_size;
    const float* x       = (const float*)d_in[0];
    const int*   ei      = (const int*)d_in[1];     // int32 per harness convention
    const float* proj_w  = (const float*)d_in[2];
    const float* proj_b  = (const float*)d_in[3];
    const float* conv_w  = (const float*)d_in[4];
    const float* conv_b  = (const float*)d_in[5];
    const float* out_w   = (const float*)d_in[6];
    const float* out_b   = (const float*)d_in[7];
    const float* b_noise = (const float*)d_in[8];
    const float* eps_n   = (const float*)d_in[9];
    float*       out     = (float*)d_out;

    char* w = (char*)d_ws;
    size_t off = 0;
    auto alloc = [&](size_t bytes) -> char* {
        char* p = w + off;
        off = (off + bytes + 255) & ~(size_t)255;
        return p;
    };
    float* h0b   = (float*)alloc((size_t)N_NODES * HID * 4);
    float* hA    = (float*)alloc((size_t)N_NODES * HID * 4);   // final h
    float* hqA   = (float*)alloc((size_t)N_NODES * HID * 4);   // quantized ping
    float* hqB   = (float*)alloc((size_t)N_NODES * HID * 4);   // quantized pong
    float* dis   = (float*)alloc((size_t)N_NODES * 4);
    float* wgt   = (float*)alloc((size_t)(N_EDGES + 16) * 4);
    int*   col   = (int*)  alloc((size_t)(N_EDGES + 16) * 4);
    int*   cnt   = (int*)  alloc((size_t)N_NODES * 4);
    int*   cur   = (int*)  alloc((size_t)N_NODES * 4);
    int*   start = (int*)  alloc((size_t)N_NODES * 4);
    int*   ctr   = (int*)  alloc(256);

    // CSR build
    k_init <<<(N_NODES + 255) / 256, 256, 0, stream>>>(cnt, cur, ctr, col, wgt, N_NODES);
    k_count<<<(N_EDGES + 255) / 256, 256, 0, stream>>>(ei, cnt, N_EDGES);
    k_node <<<(N_NODES + 255) / 256, 256, 0, stream>>>(cnt, dis, start, ctr, N_NODES);
    k_fill <<<(N_EDGES + 255) / 256, 256, 0, stream>>>(ei, dis, start, cur, col, wgt, N_EDGES);

    const int ngroups = (N_NODES + 63) / 64;    // 782
    const float deltas[NLAYER] = {1.0f, 0.5f, 0.25f};

    // h0 = x @ proj_w + proj_b; also hqA = quantize(h0, b_noise[0], delta0)
    k_gemm<false, true, true><<<ngroups, 384, 0, stream>>>(
        x, IN_C, IN_C, nullptr, 1.f, 1.f, proj_w, proj_b, h0b,
        b_noise, deltas[0], 1.0f / deltas[0], hqA);

    // fused layers: gather(hq) -> @conv_w -> +cb +eps -> relu -> quantize(next)
    const float* hin = hqA;
    for (int k = 0; k < NLAYER; k++) {
        int lastl = (k == NLAYER - 1);
        float dn = lastl ? 1.f : deltas[k + 1];
        float* ho = lastl ? hA : (hin == hqA ? hqB : hqA);
        k_layer<<<ngroups, 384, 0, stream>>>(
            hin, col, wgt, start, cnt, dis,
            conv_w + (size_t)k * HID * HID,
            conv_b + (size_t)k * HID,
            eps_n + (size_t)k * N_NODES * HID,
            lastl ? nullptr : b_noise + (size_t)(k + 1) * N_NODES * HID,
            dn, 1.0f / dn,
            ho, lastl ? 0 : 1);
        hin = ho;
    }

    const int ogroups = (N_NODES + 95) / 96;    // 521
    k_out2<<<ogroups, 384, 0, stream>>>(h0b, hA, out_w, out_b, out);
}